// Round 3
// baseline (425.222 us; speedup 1.0000x reference)
//
#include <hip/hip_runtime.h>

// ---------------------------------------------------------------------------
// SparseMultiHeadAttention: N=32768 pts, C=512, H=8, D=64, 8^3 windows (64x512)
// Pipeline: transpose W -> gather x (window-sorted, bf16) -> QKV GEMM + fused
// RMSnorm epilogue -> windowed flash attention -> output GEMM (scatter rows).
// ---------------------------------------------------------------------------

typedef __attribute__((ext_vector_type(4))) float f32x4;
typedef __attribute__((ext_vector_type(8))) short s16x8;

#define MFMA(a, b, c) __builtin_amdgcn_mfma_f32_16x16x32_bf16((a), (b), (c), 0, 0, 0)

__device__ __forceinline__ short f2bf(float f) {
  union { float f; unsigned u; } v; v.f = f;
  unsigned r = v.u + 0x7fffu + ((v.u >> 16) & 1u);
  return (short)(r >> 16);
}

// async global->LDS, 16B per lane; lds ptr must be wave-uniform base
__device__ __forceinline__ void gload16(const void* g, void* l) {
  __builtin_amdgcn_global_load_lds(
      (const __attribute__((address_space(1))) unsigned int*)g,
      (__attribute__((address_space(3))) unsigned int*)l, 16, 0, 0);
}

// ---------------- W transpose + bf16 convert: w[K][N] -> wt[N][K] -----------
__global__ __launch_bounds__(256) void transpose_w(const float* __restrict__ w,
                                                   short* __restrict__ wt,
                                                   int Ncols) {
  __shared__ float tile[64][65];
  const int t = threadIdx.x;
  const int ntn = Ncols >> 6;
  const int bk = blockIdx.x / ntn, bn = blockIdx.x % ntn;
  const int c = t & 63, r0 = t >> 6;
#pragma unroll
  for (int i = 0; i < 16; ++i) {
    int k = i * 4 + r0;
    tile[k][c] = w[(size_t)(bk * 64 + k) * Ncols + bn * 64 + c];
  }
  __syncthreads();
#pragma unroll
  for (int i = 0; i < 16; ++i) {
    int n = i * 4 + r0;
    wt[(size_t)(bn * 64 + n) * 512 + bk * 64 + c] = f2bf(tile[c][n]);
  }
}

// ------------- gather x into window-sorted order, fp32 -> bf16 --------------
__global__ __launch_bounds__(256) void gather_x(const float* __restrict__ x,
                                                const int* __restrict__ coords,
                                                short* __restrict__ xs,
                                                int* __restrict__ nofp) {
  const int t = threadIdx.x, lane = t & 63, wid = t >> 6;
  const int n = blockIdx.x * 4 + wid;
  const int cx = coords[n * 4 + 1], cy = coords[n * 4 + 2], cz = coords[n * 4 + 3];
  const int w = ((cx >> 3) * 4 + (cy >> 3)) * 4 + (cz >> 3);
  const int r = ((cz & 7) << 6) | ((cy & 7) << 3) | (cx & 7);
  const int p = w * 512 + r;
  const f32x4* xr = (const f32x4*)(x + (size_t)n * 512);
  f32x4 v0 = xr[lane * 2], v1 = xr[lane * 2 + 1];
  s16x8 o;
  o[0] = f2bf(v0[0]); o[1] = f2bf(v0[1]); o[2] = f2bf(v0[2]); o[3] = f2bf(v0[3]);
  o[4] = f2bf(v1[0]); o[5] = f2bf(v1[1]); o[6] = f2bf(v1[2]); o[7] = f2bf(v1[3]);
  *(s16x8*)(xs + (size_t)p * 512 + lane * 8) = o;
  if (lane == 0) nofp[p] = n;
}

// ---------------- QKV GEMM (M=32768,K=512,N=1536) + fused RMSnorm ----------
// A = xs[M][512] bf16 (window-sorted rows), Bt = wqkvt[1536][512] bf16.
// Epilogue: +bias, rms-norm q/k per (row, head), write Qs/Ks row-major and
// Vt transposed ([wh][d][m]).  1/sqrt(D) folded into Q scale.
__global__ __launch_bounds__(256) void gemm_qkv(
    const short* __restrict__ xs, const short* __restrict__ wt,
    const float* __restrict__ bqkv, const float* __restrict__ gq,
    const float* __restrict__ gk, short* __restrict__ Qs,
    short* __restrict__ Ks, short* __restrict__ Vt) {
  __shared__ short As[128 * 32];
  __shared__ short Bs[128 * 32];
  const int t = threadIdx.x, lane = t & 63, wid = t >> 6;
  const int bm = blockIdx.x / 12, bn = blockIdx.x % 12;
  const int wr = wid >> 1, wc = wid & 1;
  const int rowbase = bm * 128, colbase = bn * 128;
  f32x4 acc[4][4];
#pragma unroll
  for (int m = 0; m < 4; ++m)
#pragma unroll
    for (int n = 0; n < 4; ++n) acc[m][n] = (f32x4){0.f, 0.f, 0.f, 0.f};

  const int srow = lane >> 2, sslot = lane & 3;
  for (int kt = 0; kt < 16; ++kt) {
#pragma unroll
    for (int i = 0; i < 2; ++i) {
      int row = i * 64 + wid * 16 + srow;
      int gc = sslot ^ ((row >> 2) & 3);
      gload16(xs + (size_t)(rowbase + row) * 512 + kt * 32 + gc * 8,
              &As[(i * 64 + wid * 16) * 32]);
      gload16(wt + (size_t)(colbase + row) * 512 + kt * 32 + gc * 8,
              &Bs[(i * 64 + wid * 16) * 32]);
    }
    __syncthreads();
    s16x8 af[4], bfr[4];
#pragma unroll
    for (int m = 0; m < 4; ++m) {
      int row = wr * 64 + m * 16 + (lane & 15);
      int ch = (lane >> 4) ^ ((row >> 2) & 3);
      af[m] = *(const s16x8*)&As[row * 32 + ch * 8];
    }
#pragma unroll
    for (int n = 0; n < 4; ++n) {
      int row = wc * 64 + n * 16 + (lane & 15);
      int ch = (lane >> 4) ^ ((row >> 2) & 3);
      bfr[n] = *(const s16x8*)&Bs[row * 32 + ch * 8];
    }
#pragma unroll
    for (int m = 0; m < 4; ++m)
#pragma unroll
      for (int n = 0; n < 4; ++n) acc[m][n] = MFMA(af[m], bfr[n], acc[m][n]);
    __syncthreads();
  }

  // epilogue: this wave's 64 cols are exactly one (which, head) D-group
  const int wcb = colbase + wc * 64;
  const int which = wcb >> 9;
  const int h = (wcb >> 6) & 7;
  float bias[4], gam[4];
#pragma unroll
  for (int n = 0; n < 4; ++n) {
    int d = n * 16 + (lane & 15);
    bias[n] = bqkv[wcb + d];
    gam[n] = (which == 0) ? gq[h * 64 + d] : (which == 1) ? gk[h * 64 + d] : 1.0f;
  }
#pragma unroll
  for (int m = 0; m < 4; ++m) {
#pragma unroll
    for (int n = 0; n < 4; ++n)
#pragma unroll
      for (int j = 0; j < 4; ++j) acc[m][n][j] += bias[n];
    float scl[4] = {1.f, 1.f, 1.f, 1.f};
    if (which < 2) {
      float ss[4] = {0.f, 0.f, 0.f, 0.f};
#pragma unroll
      for (int n = 0; n < 4; ++n)
#pragma unroll
        for (int j = 0; j < 4; ++j) ss[j] += acc[m][n][j] * acc[m][n][j];
#pragma unroll
      for (int j = 0; j < 4; ++j) {
#pragma unroll
        for (int msk = 1; msk < 16; msk <<= 1) ss[j] += __shfl_xor(ss[j], msk, 64);
        float nrm = fmaxf(sqrtf(ss[j]), 1e-12f);
        // q: gamma*sqrt(D)/nrm * (1/sqrt(D)) = gamma/nrm ; k: gamma*8/nrm
        scl[j] = ((which == 0) ? 1.0f : 8.0f) / nrm;
      }
    }
#pragma unroll
    for (int j = 0; j < 4; ++j) {
      int p = rowbase + wr * 64 + m * 16 + (lane >> 4) * 4 + j;
      int w = p >> 9, mm = p & 511;
#pragma unroll
      for (int n = 0; n < 4; ++n) {
        int d = n * 16 + (lane & 15);
        float v = acc[m][n][j];
        if (which == 0)
          Qs[((w * 8 + h) * 512 + mm) * 64 + d] = f2bf(v * gam[n] * scl[j]);
        else if (which == 1)
          Ks[((w * 8 + h) * 512 + mm) * 64 + d] = f2bf(v * gam[n] * scl[j]);
        else
          Vt[((w * 8 + h) * 64 + d) * 512 + mm] = f2bf(v);
      }
    }
  }
}

// ---------------- windowed flash attention --------------------------------
// block = one (window,head) x 128-query tile; 4 waves, 32 q-rows each.
// K-tiles of 128 keys; online softmax; P via swizzled LDS round-trip.
__global__ __launch_bounds__(256) void attn_k(const short* __restrict__ Qs,
                                              const short* __restrict__ Ks,
                                              const short* __restrict__ Vt,
                                              short* __restrict__ Hs) {
  extern __shared__ short smem[];
  short* Kl = smem;               // [128][64]
  short* Vl = smem + 128 * 64;    // [64][128]
  short* Pl = smem + 2 * 128 * 64;  // [128][128]
  const int t = threadIdx.x, lane = t & 63, wid = t >> 6;
  const int qt = blockIdx.x & 3, wh = blockIdx.x >> 2;
  const short* Qb = Qs + (size_t)wh * 512 * 64;
  const short* Kb = Ks + (size_t)wh * 512 * 64;
  const short* Vb = Vt + (size_t)wh * 64 * 512;

  s16x8 aq[2][2];
#pragma unroll
  for (int m = 0; m < 2; ++m)
#pragma unroll
    for (int ks = 0; ks < 2; ++ks) {
      int row = qt * 128 + wid * 32 + m * 16 + (lane & 15);
      aq[m][ks] = *(const s16x8*)&Qb[row * 64 + ks * 32 + (lane >> 4) * 8];
    }
  f32x4 oacc[2][4];
  float rm[2][4], rl[2][4];
#pragma unroll
  for (int m = 0; m < 2; ++m) {
#pragma unroll
    for (int n = 0; n < 4; ++n) oacc[m][n] = (f32x4){0.f, 0.f, 0.f, 0.f};
#pragma unroll
    for (int j = 0; j < 4; ++j) { rm[m][j] = -1e30f; rl[m][j] = 0.f; }
  }

  for (int kt = 0; kt < 4; ++kt) {
    __syncthreads();  // protect previous iteration's K/V reads
#pragma unroll
    for (int i = 0; i < 4; ++i) {
      int row = i * 32 + wid * 8 + (lane >> 3);
      int gc = (lane & 7) ^ (row & 7);
      gload16(Kb + (size_t)(kt * 128 + row) * 64 + gc * 8,
              &Kl[(i * 32 + wid * 8) * 64]);
    }
#pragma unroll
    for (int i = 0; i < 4; ++i) {
      int dr = i * 16 + wid * 4 + (lane >> 4);
      int gc = (lane & 15) ^ (dr & 15);
      gload16(Vb + (size_t)dr * 512 + kt * 128 + gc * 8,
              &Vl[(i * 16 + wid * 4) * 128]);
    }
    __syncthreads();

    f32x4 s[2][8];
#pragma unroll
    for (int m = 0; m < 2; ++m)
#pragma unroll
      for (int n = 0; n < 8; ++n) s[m][n] = (f32x4){0.f, 0.f, 0.f, 0.f};
#pragma unroll
    for (int ks = 0; ks < 2; ++ks)
#pragma unroll
      for (int n = 0; n < 8; ++n) {
        int kr = n * 16 + (lane & 15);
        int ch = (ks * 4 + (lane >> 4)) ^ (kr & 7);
        s16x8 bk = *(const s16x8*)&Kl[kr * 64 + ch * 8];
        s[0][n] = MFMA(aq[0][ks], bk, s[0][n]);
        s[1][n] = MFMA(aq[1][ks], bk, s[1][n]);
      }

    // online softmax per row (rows: (lane>>4)*4+j within m-tile)
#pragma unroll
    for (int m = 0; m < 2; ++m)
#pragma unroll
      for (int j = 0; j < 4; ++j) {
        float v = s[m][0][j];
#pragma unroll
        for (int n = 1; n < 8; ++n) v = fmaxf(v, s[m][n][j]);
#pragma unroll
        for (int msk = 1; msk < 16; msk <<= 1) v = fmaxf(v, __shfl_xor(v, msk, 64));
        float nm = fmaxf(rm[m][j], v);
        float f = __expf(rm[m][j] - nm);
        rm[m][j] = nm;
        float sum = 0.f;
#pragma unroll
        for (int n = 0; n < 8; ++n) {
          float pe = __expf(s[m][n][j] - nm);
          s[m][n][j] = pe;
          sum += pe;
        }
#pragma unroll
        for (int msk = 1; msk < 16; msk <<= 1) sum += __shfl_xor(sum, msk, 64);
        rl[m][j] = rl[m][j] * f + sum;
#pragma unroll
        for (int n2 = 0; n2 < 4; ++n2) oacc[m][n2][j] *= f;
      }

    // P -> LDS (swizzled), wave-local slab
#pragma unroll
    for (int m = 0; m < 2; ++m)
#pragma unroll
      for (int n = 0; n < 8; ++n)
#pragma unroll
        for (int j = 0; j < 4; ++j) {
          int row = wid * 32 + m * 16 + (lane >> 4) * 4 + j;
          int col = n * 16 + (lane & 15);
          int ch = (col >> 3) ^ (row & 15);
          Pl[row * 128 + ch * 8 + (col & 7)] = f2bf(s[m][n][j]);
        }

    // PV
#pragma unroll
    for (int ks = 0; ks < 4; ++ks) {
      s16x8 ap[2];
#pragma unroll
      for (int m = 0; m < 2; ++m) {
        int row = wid * 32 + m * 16 + (lane & 15);
        int ch = (ks * 4 + (lane >> 4)) ^ (row & 15);
        ap[m] = *(const s16x8*)&Pl[row * 128 + ch * 8];
      }
#pragma unroll
      for (int n2 = 0; n2 < 4; ++n2) {
        int dr = n2 * 16 + (lane & 15);
        int ch = (ks * 4 + (lane >> 4)) ^ (dr & 15);
        s16x8 bv = *(const s16x8*)&Vl[dr * 128 + ch * 8];
        oacc[0][n2] = MFMA(ap[0], bv, oacc[0][n2]);
        oacc[1][n2] = MFMA(ap[1], bv, oacc[1][n2]);
      }
    }
  }

  const int w = wh >> 3, hh = wh & 7;
#pragma unroll
  for (int m = 0; m < 2; ++m)
#pragma unroll
    for (int j = 0; j < 4; ++j) {
      float inv = 1.0f / rl[m][j];
      int row = qt * 128 + wid * 32 + m * 16 + (lane >> 4) * 4 + j;
      int p = w * 512 + row;
#pragma unroll
      for (int n2 = 0; n2 < 4; ++n2) {
        int d = n2 * 16 + (lane & 15);
        Hs[(size_t)p * 512 + hh * 64 + d] = f2bf(oacc[m][n2][j] * inv);
      }
    }
}

// ---------------- output GEMM (M=32768,K=512,N=512), scatter rows ----------
__global__ __launch_bounds__(256) void gemm_out_k(
    const short* __restrict__ Hs, const short* __restrict__ wt,
    const float* __restrict__ bout, const int* __restrict__ nofp,
    float* __restrict__ out) {
  __shared__ short As[128 * 32];
  __shared__ short Bs[128 * 32];
  const int t = threadIdx.x, lane = t & 63, wid = t >> 6;
  const int bm = blockIdx.x >> 2, bn = blockIdx.x & 3;
  const int wr = wid >> 1, wc = wid & 1;
  const int rowbase = bm * 128, colbase = bn * 128;
  f32x4 acc[4][4];
#pragma unroll
  for (int m = 0; m < 4; ++m)
#pragma unroll
    for (int n = 0; n < 4; ++n) acc[m][n] = (f32x4){0.f, 0.f, 0.f, 0.f};

  const int srow = lane >> 2, sslot = lane & 3;
  for (int kt = 0; kt < 16; ++kt) {
#pragma unroll
    for (int i = 0; i < 2; ++i) {
      int row = i * 64 + wid * 16 + srow;
      int gc = sslot ^ ((row >> 2) & 3);
      gload16(Hs + (size_t)(rowbase + row) * 512 + kt * 32 + gc * 8,
              &As[(i * 64 + wid * 16) * 32]);
      gload16(wt + (size_t)(colbase + row) * 512 + kt * 32 + gc * 8,
              &Bs[(i * 64 + wid * 16) * 32]);
    }
    __syncthreads();
    s16x8 af[4], bfr[4];
#pragma unroll
    for (int m = 0; m < 4; ++m) {
      int row = wr * 64 + m * 16 + (lane & 15);
      int ch = (lane >> 4) ^ ((row >> 2) & 3);
      af[m] = *(const s16x8*)&As[row * 32 + ch * 8];
    }
#pragma unroll
    for (int n = 0; n < 4; ++n) {
      int row = wc * 64 + n * 16 + (lane & 15);
      int ch = (lane >> 4) ^ ((row >> 2) & 3);
      bfr[n] = *(const s16x8*)&Bs[row * 32 + ch * 8];
    }
#pragma unroll
    for (int m = 0; m < 4; ++m)
#pragma unroll
      for (int n = 0; n < 4; ++n) acc[m][n] = MFMA(af[m], bfr[n], acc[m][n]);
    __syncthreads();
  }
#pragma unroll
  for (int m = 0; m < 4; ++m)
#pragma unroll
    for (int j = 0; j < 4; ++j) {
      int p = rowbase + wr * 64 + m * 16 + (lane >> 4) * 4 + j;
      int norig = nofp[p];
#pragma unroll
      for (int n = 0; n < 4; ++n) {
        int c = colbase + wc * 64 + n * 16 + (lane & 15);
        out[(size_t)norig * 512 + c] = acc[m][n][j] + bout[c];
      }
    }
}

// ---------------------------------------------------------------------------
extern "C" void kernel_launch(void* const* d_in, const int* in_sizes, int n_in,
                              void* d_out, int out_size, void* d_ws,
                              size_t ws_size, hipStream_t stream) {
  const float* x      = (const float*)d_in[0];
  const int*   coords = (const int*)d_in[1];
  const float* wqkv   = (const float*)d_in[2];
  const float* bqkv   = (const float*)d_in[3];
  const float* gq     = (const float*)d_in[4];
  const float* gk     = (const float*)d_in[5];
  const float* wout   = (const float*)d_in[6];
  const float* bout   = (const float*)d_in[7];
  float* out = (float*)d_out;
  char* ws = (char*)d_ws;

  short* xs    = (short*)(ws + 0);            // 32 MB  [32768][512] bf16 sorted
  short* wqkvt = (short*)(ws + 33554432);     // 1.5 MB [1536][512] bf16
  short* woutt = (short*)(ws + 35127296);     // 0.5 MB [512][512]  bf16
  short* Qs    = (short*)(ws + 35651584);     // 32 MB  [wh][512][64]
  short* Ks    = (short*)(ws + 69206016);     // 32 MB  [wh][512][64]
  short* Vt    = (short*)(ws + 102760448);    // 32 MB  [wh][64][512]
  short* Hs    = (short*)(ws + 136314880);    // 32 MB  [32768][512]
  int*   nofp  = (int*)(ws + 169869312);      // 128 KB

  transpose_w<<<dim3(192), dim3(256), 0, stream>>>(wqkv, wqkvt, 1536);
  transpose_w<<<dim3(64), dim3(256), 0, stream>>>(wout, woutt, 512);
  gather_x<<<dim3(8192), dim3(256), 0, stream>>>(x, coords, xs, nofp);
  gemm_qkv<<<dim3(3072), dim3(256), 0, stream>>>(xs, wqkvt, bqkv, gq, gk, Qs, Ks, Vt);
  attn_k<<<dim3(2048), dim3(256), 65536, stream>>>(Qs, Ks, Vt, Hs);
  gemm_out_k<<<dim3(1024), dim3(256), 0, stream>>>(Hs, woutt, bout, nofp, out);
}